// Round 10
// baseline (227.730 us; speedup 1.0000x reference)
//
#include <hip/hip_runtime.h>
#include <stdint.h>

#define NM 16
#define HW_P 589824            // 768*768 pixels per mask
#define U8PM 9216              // u64 words per mask
#define U8PH 4608              // u64 words per HALF mask
#define F4PM 147456            // float4s per mask
#define F4PT 2359296           // float4s per tensor
#define PT 512                 // pipeline threads per WG
#define NG 8                   // column groups (2 columns each)
#define NW 16                  // pipeline WGs = NG * 2 halves
#define EWG 128                // election WGs (128/8 XCDs -> some XCD >= 16)

typedef unsigned long long u64;
typedef float vf4 __attribute__((ext_vector_type(4)));

// meta words: [0..7] cnt[xcc] | [8] winner | [16..31] flagsA | [32..47] flagsB
// | [48 + ch*4] cons (ch = g*2+h, 16B apart)
// | [112 + (ch*16+t)*4] prodflag: bit0 valid | bits1..20 pca | bit21 fa
// | word 1024+: xchg u64 pairs, slot (ch*2 + (t&1)); tag in bits 40..44

__device__ __forceinline__ unsigned aload(const unsigned* p) {
    return __hip_atomic_load(p, __ATOMIC_RELAXED, __HIP_MEMORY_SCOPE_AGENT);
}
__device__ __forceinline__ void astore(unsigned* p, unsigned v) {
    __hip_atomic_store(p, v, __ATOMIC_RELAXED, __HIP_MEMORY_SCOPE_AGENT);
}
__device__ __forceinline__ unsigned afadd(unsigned* p, unsigned v) {
    return __hip_atomic_fetch_add(p, v, __ATOMIC_RELAXED, __HIP_MEMORY_SCOPE_AGENT);
}
__device__ __forceinline__ u64 aload64(const u64* p) {
    return __hip_atomic_load(p, __ATOMIC_RELAXED, __HIP_MEMORY_SCOPE_AGENT);
}
__device__ __forceinline__ void astore64(u64* p, u64 v) {
    __hip_atomic_store(p, v, __ATOMIC_RELAXED, __HIP_MEMORY_SCOPE_AGENT);
}

__device__ __forceinline__ uint32_t spread4(uint32_t x) {
    uint32_t t = (x | (x << 12)) & 0x000F000Fu;
    t = (t | (t << 6)) & 0x03030303u;
    t = (t | (t << 3)) & 0x11111111u;
    return t;
}

// ---------------- kernel 1: binarize (coalesced) + meta zero ---------------
__global__ __launch_bounds__(256) void binarize_kernel(
    const float* __restrict__ ma, const float* __restrict__ mb,
    uint32_t* __restrict__ bitsA, uint32_t* __restrict__ bitsB,
    uint4* __restrict__ meta4)
{
    if (blockIdx.x == 0) {          // zero 8 KB of control state (ws is 0xAA)
        uint4 z; z.x = z.y = z.z = z.w = 0u;
        meta4[threadIdx.x] = z;
        meta4[threadIdx.x + 256] = z;
    }
    int g = blockIdx.x * 256 + threadIdx.x;        // float4 index
    int tensor = (g >= F4PT);                      // %64==0: wave-uniform
    int lg = tensor ? (g - F4PT) : g;
    const float* src = tensor ? mb : ma;
    vf4 v = __builtin_nontemporal_load(((const vf4*)src) + lg);
    u64 q0 = __ballot(v.x > 0.0f);
    u64 q1 = __ballot(v.y > 0.0f);
    u64 q2 = __ballot(v.z > 0.0f);
    u64 q3 = __ballot(v.w > 0.0f);
    int lane = threadIdx.x & 63;
    if (lane < 8) {
        uint32_t wd = spread4((uint32_t)(q0 >> (8 * lane)) & 0xFFu)
                    | (spread4((uint32_t)(q1 >> (8 * lane)) & 0xFFu) << 1)
                    | (spread4((uint32_t)(q2 >> (8 * lane)) & 0xFFu) << 2)
                    | (spread4((uint32_t)(q3 >> (8 * lane)) & 0xFFu) << 3);
        uint32_t* bits = tensor ? bitsB : bitsA;
        bits[((lg & ~63) >> 3) + lane] = wd;       // word = 8 float4s
    }
}

// ---------------- kernel 2: split-half systolic pipeline -------------------
// 8 column-groups x 2 half-WGs = 16 WGs on ONE XCD (election over 128).
// Each WG moves only HALF a row (36 KB) per stage -> per-CU memory-port
// bytes halve vs R9. Halves exchange 4 partial popcounts through L2 (tagged
// u64s, tag rides with data) and make bit-identical redundant decisions.
__global__ __launch_bounds__(PT, 1) void pipeline_kernel(
    const float* __restrict__ sa, const float* __restrict__ sb,
    uint32_t* bitsA, uint32_t* bitsB, unsigned* meta, u64* msg)
{
    unsigned* cnt    = meta;
    unsigned* winner = meta + 8;
    int* flagsA      = (int*)(meta + 16);
    int* flagsB      = (int*)(meta + 32);
    unsigned* consF  = meta + 48;
    unsigned* prodF  = meta + 112;
    u64* xchg        = (u64*)(meta + 1024);

    const int tid = threadIdx.x;
    const int wave = tid >> 6, lane = tid & 63;

    __shared__ int s_slot;
    __shared__ int4 part[8];

    // ---- election: first XCD to assemble 16 WGs wins; losers exit ----
    if (tid == 0) {
        int xcc;
        asm volatile("s_getreg_b32 %0, hwreg(HW_REG_XCC_ID)" : "=s"(xcc));
        xcc &= 7;
        unsigned slot = afadd(&cnt[xcc], 1u);
        int mine = -1;
        if (slot < NW) {
            if (slot == NW - 1) {
                unsigned exp = 0u;
                __hip_atomic_compare_exchange_strong(
                    winner, &exp, (unsigned)(xcc + 1),
                    __ATOMIC_RELAXED, __ATOMIC_RELAXED, __HIP_MEMORY_SCOPE_AGENT);
            }
            unsigned w;
            while (!(w = aload(winner))) __builtin_amdgcn_s_sleep(1);
            if (w == (unsigned)(xcc + 1)) mine = (int)slot;
        }
        s_slot = mine;
    }
    __syncthreads();
    const int sl = s_slot;
    if (sl < 0) return;
    const int g = sl >> 1, h = sl & 1;
    const int ch = g * 2 + h;            // my producer channel
    const int inch = (g - 1) * 2 + h;    // upstream channel (g>0)

    u64* A8 = (u64*)bitsA;
    u64* B8 = (u64*)bitsB;

    // half-row per-thread: 4 x dwordx4 (u64 idx 2*tid+1024w) + 1 x u64 tail
    auto load9 = [&](const u64* base, u64* dst) {
        const uint4* b4 = (const uint4*)base;
#pragma unroll
        for (int w = 0; w < 4; ++w) {
            uint4 q = b4[tid + PT * w];
            dst[2 * w]     = ((u64)q.y << 32) | q.x;
            dst[2 * w + 1] = ((u64)q.w << 32) | q.z;
        }
        dst[8] = base[4096 + tid];
    };
    auto load9_agent = [&](const u64* base, u64* dst) {
#pragma unroll
        for (int w = 0; w < 4; ++w) {
            int i2 = 2 * tid + 1024 * w;
            dst[2 * w]     = aload64(&base[i2]);
            dst[2 * w + 1] = aload64(&base[i2 + 1]);
        }
        dst[8] = aload64(&base[4096 + tid]);
    };
    auto store9 = [&](u64* base, const u64* src) {
        uint4* b4 = (uint4*)base;
#pragma unroll
        for (int w = 0; w < 4; ++w) {
            uint4 q;
            q.x = (uint32_t)src[2 * w];     q.y = (uint32_t)(src[2 * w] >> 32);
            q.z = (uint32_t)src[2 * w + 1]; q.w = (uint32_t)(src[2 * w + 1] >> 32);
            b4[tid + PT * w] = q;
        }
        base[4096 + tid] = src[8];
    };

    // ---- b columns (my half) + half popcounts ----
    const int c0 = 2 * g, c1 = 2 * g + 1;
    u64 b0[9], b1[9];
    load9(B8 + (size_t)c0 * U8PM + (size_t)h * U8PH, b0);
    load9(B8 + (size_t)c1 * U8PM + (size_t)h * U8PH, b1);
    int v0 = 0, v1 = 0;
#pragma unroll
    for (int w = 0; w < 9; ++w) { v0 += __popcll(b0[w]); v1 += __popcll(b1[w]); }
#pragma unroll
    for (int off = 32; off >= 1; off >>= 1) {
        v0 += __shfl_xor(v0, off); v1 += __shfl_xor(v1, off);
    }
    if (lane == 0) { int4 p; p.x = v0; p.y = v1; p.z = 0; p.w = 0; part[wave] = p; }
    __syncthreads();
    int pcb0h = 0, pcb1h = 0;
#pragma unroll
    for (int w = 0; w < 8; ++w) { pcb0h += part[w].x; pcb1h += part[w].y; }
    __syncthreads();   // part[] free for stage 0

    // ---- init exchange (parity 1, tag 1): column popcount totals ----
    {
        u64* myx = xchg + (size_t)(ch * 2 + 1) * 2;
        if (tid == 0)
            astore64(&myx[0], (u64)pcb0h | ((u64)pcb1h << 20) | (1ull << 40));
    }
    int pcb0, pcb1;
    {
        const u64* px = xchg + (size_t)((g * 2 + (1 - h)) * 2 + 1) * 2;
        u64 x0;
        do { x0 = aload64(&px[0]); } while ((unsigned)(x0 >> 40) != 1u);
        pcb0 = pcb0h + (int)(x0 & 0xFFFFF);
        pcb1 = pcb1h + (int)((x0 >> 20) & 0xFFFFF);
    }
    float sb0 = sb[c0], sb1 = sb[c1];
    int fb0 = 0, fb1 = 0;

    for (int t = 0; t < NM; ++t) {
        int pca, fa;
        u64 a[9];

        // ---- obtain row t (my half) ----
        if (g == 0) {
            load9(A8 + (size_t)t * U8PM + (size_t)h * U8PH, a);
            pca = 0; fa = 0;
        } else {
            const unsigned* fptr = &prodF[(inch * 16 + t) * 4];
            unsigned v;
            do { v = aload(fptr); } while (!v);
            asm volatile("" ::: "memory");   // pin data loads below the poll
            pca = (int)((v >> 1) & 0xFFFFFu);
            fa  = (int)((v >> 21) & 1u);
            load9_agent(msg + (size_t)(inch * 4 + (t & 3)) * U8PH, a);
        }

        // ---- half popc terms ----
        int i0 = 0, i1 = 0, itr = 0, ipc = 0;
#pragma unroll
        for (int w = 0; w < 9; ++w) {
            u64 ab0 = a[w] & b0[w];
            i0 += __popcll(ab0);
            i1 += __popcll(a[w] & b1[w]);
            itr += __popcll(ab0 & b1[w]);
        }
        if (g == 0) {
#pragma unroll
            for (int w = 0; w < 9; ++w) ipc += __popcll(a[w]);
        }
#pragma unroll
        for (int off = 32; off >= 1; off >>= 1) {
            i0 += __shfl_xor(i0, off); i1 += __shfl_xor(i1, off);
            itr += __shfl_xor(itr, off); ipc += __shfl_xor(ipc, off);
        }
        if (lane == 0) {
            int4 p; p.x = i0; p.y = i1; p.z = itr; p.w = ipc; part[wave] = p;
        }
        __syncthreads();   // B2: partials visible, slot loads retired
        if (g > 0 && tid == 65)            // slot consumed -> credit
            astore(&consF[inch * 4], (unsigned)(t + 1));
        int I0h = 0, I1h = 0, Th = 0, PCh = 0;
#pragma unroll
        for (int w = 0; w < 8; ++w) {
            int4 p = part[w];
            I0h += p.x; I1h += p.y; Th += p.z; PCh += p.w;
        }

        // ---- cross-half exchange (tags 2..17, no wrap; skew <= 1 row) ----
        unsigned tg = (unsigned)(t + 2);
        {
            u64* myx = xchg + (size_t)(ch * 2 + (t & 1)) * 2;
            if (tid == 0) {
                astore64(&myx[0], (u64)I0h | ((u64)I1h << 20) | ((u64)tg << 40));
                astore64(&myx[1], (u64)Th  | ((u64)PCh << 20) | ((u64)tg << 40));
            }
        }
        int I0, I1, T, PC;
        {
            const u64* px = xchg + (size_t)((g * 2 + (1 - h)) * 2 + (t & 1)) * 2;
            u64 x0, x1;
            do { x0 = aload64(&px[0]); } while ((unsigned)(x0 >> 40) != tg);
            do { x1 = aload64(&px[1]); } while ((unsigned)(x1 >> 40) != tg);
            I0 = I0h + (int)(x0 & 0xFFFFF);
            I1 = I1h + (int)((x0 >> 20) & 0xFFFFF);
            T  = Th  + (int)(x1 & 0xFFFFF);
            PC = PCh + (int)((x1 >> 20) & 0xFFFFF);
        }
        if (g == 0) pca = PC;

        float sai = sa[t];
        // ---- pair (t,c0): replicate reference fp32 arithmetic exactly;
        //      decisions identical in both halves (same totals, same fp ops) --
        bool aupd = false;
        {
            int inter = I0;
            int uni = pca + pcb0 - inter;
            float iou = (float)inter / fmaxf((float)uni, 1.0f);
            bool aw = sai > sb0;
            if (iou > 0.8f) { if (aw) fb0 = 1; else fa = 1; }
            else if (inter > 0) {
                if (aw) {
                    pcb0 -= inter;
#pragma unroll
                    for (int w = 0; w < 9; ++w) b0[w] &= ~a[w];
                } else {
                    pca -= inter; aupd = true;
#pragma unroll
                    for (int w = 0; w < 9; ++w) a[w] &= ~b0[w];
                }
            }
        }
        // ---- pair (t,c1): exact inter via speculative triple term ----
        {
            int inter = aupd ? (I1 - T) : I1;
            int uni = pca + pcb1 - inter;
            float iou = (float)inter / fmaxf((float)uni, 1.0f);
            bool aw = sai > sb1;
            if (iou > 0.8f) { if (aw) fb1 = 1; else fa = 1; }
            else if (inter > 0) {
                if (aw) {
                    pcb1 -= inter;
#pragma unroll
                    for (int w = 0; w < 9; ++w) b1[w] &= ~a[w];
                } else {
                    pca -= inter;
#pragma unroll
                    for (int w = 0; w < 9; ++w) a[w] &= ~b1[w];
                }
            }
        }

        // ---- forward / finalize row (my half) ----
        if (g < NG - 1) {
            if (t >= 4) {   // wave-autonomous credit check (rarely blocks)
                const unsigned* cp = &consF[ch * 4];
                while (aload(cp) < (unsigned)(t - 3)) {}
                asm volatile("" ::: "memory");
            }
            store9(msg + (size_t)(ch * 4 + (t & 3)) * U8PH, a);
            __syncthreads();   // B3: every wave's vmcnt(0) -> data in L2
            if (tid == 0)      // flag strictly after data
                astore(&prodF[(ch * 16 + t) * 4],
                       1u | ((unsigned)pca << 1) | ((unsigned)fa << 21));
        } else {
            store9(A8 + (size_t)t * U8PM + (size_t)h * U8PH, a);
            if (h == 0 && tid == 0) flagsA[t] = fa;
            __syncthreads();   // part[] anti-race across stages
        }
    }

    // final b columns (my half) + flags; dispatch-end flush publishes
    store9(B8 + (size_t)c0 * U8PM + (size_t)h * U8PH, b0);
    store9(B8 + (size_t)c1 * U8PM + (size_t)h * U8PH, b1);
    if (h == 0 && tid == 0) { flagsB[c0] = fb0; flagsB[c1] = fb1; }
}

// ---------------- kernel 3: expand (coalesced, NT stores) ------------------
__global__ __launch_bounds__(256) void expand_kernel(
    const uint32_t* __restrict__ bitsA, const uint32_t* __restrict__ bitsB,
    const int* __restrict__ meta, float* __restrict__ out)
{
    int g = blockIdx.x * 256 + threadIdx.x;        // float4 index
    int tensor = (g >= F4PT);
    int lg = tensor ? (g - F4PT) : g;
    const uint32_t* bits = tensor ? bitsB : bitsA;
    const int* flags = meta + (tensor ? 32 : 16);
    int m = lg / F4PM;
    bool keep = (flags[m] == 0);
    uint32_t wd = keep ? bits[lg >> 3] : 0u;
    int sh = (lg & 7) * 4;
    vf4 o;
    o.x = ((wd >> (sh + 0)) & 1u) ? 1.0f : 0.0f;
    o.y = ((wd >> (sh + 1)) & 1u) ? 1.0f : 0.0f;
    o.z = ((wd >> (sh + 2)) & 1u) ? 1.0f : 0.0f;
    o.w = ((wd >> (sh + 3)) & 1u) ? 1.0f : 0.0f;
    __builtin_nontemporal_store(o, ((vf4*)out) + g);
    if (g < 2 * NM) {   // keep_a / keep_b tail (flagsA,flagsB contiguous)
        out[(size_t)2 * NM * HW_P + g] = meta[16 + g] ? 0.0f : 1.0f;
    }
}

extern "C" void kernel_launch(void* const* d_in, const int* in_sizes, int n_in,
                              void* d_out, int out_size, void* d_ws, size_t ws_size,
                              hipStream_t stream)
{
    const float* ma = (const float*)d_in[0];
    const float* mb = (const float*)d_in[1];
    const float* sa = (const float*)d_in[2];
    const float* sb = (const float*)d_in[3];
    float* out = (float*)d_out;
    char* ws = (char*)d_ws;

    uint32_t* bitsA = (uint32_t*)(ws);             // 1,179,648 B
    uint32_t* bitsB = (uint32_t*)(ws + 1179648);   // 1,179,648 B
    unsigned* meta  = (unsigned*)(ws + 2359296);   // 8192 B, zeroed by binarize
    u64* msg        = (u64*)(ws + 2367488);        // 56 half-slots * 36,864 B

    binarize_kernel<<<18432, 256, 0, stream>>>(ma, mb, bitsA, bitsB,
                                               (uint4*)meta);
    pipeline_kernel<<<EWG, PT, 0, stream>>>(sa, sb, bitsA, bitsB, meta, msg);
    expand_kernel<<<18432, 256, 0, stream>>>(bitsA, bitsB, (const int*)meta, out);
}

// Round 11
// 220.539 us; speedup vs baseline: 1.0326x; 1.0326x over previous
//
#include <hip/hip_runtime.h>
#include <stdint.h>

#define NM 16
#define HW_P 589824            // 768*768 pixels per mask
#define U8PM 9216              // u64 words per mask
#define C4PM 4608              // uint4 chunks per mask
#define F4PM 147456            // float4s per mask
#define F4PT 2359296           // float4s per tensor
#define PT 512                 // pipeline threads per WG
#define NG 8                   // pipeline WGs (2 columns each)
#define EWG 64                 // election WGs (64 = 8*8: pigeonhole winner certain)

typedef unsigned long long u64;
typedef float vf4 __attribute__((ext_vector_type(4)));

// meta words: [0..7] cnt[xcc] | [8] winner | [16..31] flagsA | [32..47] flagsB
// | [80 + (g*16+t)*4] prodflag (16B apart): bit0 valid | bits1..20 pca | bit21 fa
// msg: UNIQUE slot per (boundary g, row t) -> no reuse, no credits, and the
// consumer CU has never touched a slot's addresses (stores are write-through
// no-allocate), so PLAIN coalesced dwordx4 loads are staleness-free.

__device__ __forceinline__ unsigned aload(const unsigned* p) {
    return __hip_atomic_load(p, __ATOMIC_RELAXED, __HIP_MEMORY_SCOPE_AGENT);
}
__device__ __forceinline__ void astore(unsigned* p, unsigned v) {
    __hip_atomic_store(p, v, __ATOMIC_RELAXED, __HIP_MEMORY_SCOPE_AGENT);
}
__device__ __forceinline__ unsigned afadd(unsigned* p, unsigned v) {
    return __hip_atomic_fetch_add(p, v, __ATOMIC_RELAXED, __HIP_MEMORY_SCOPE_AGENT);
}

__device__ __forceinline__ uint32_t spread4(uint32_t x) {
    uint32_t t = (x | (x << 12)) & 0x000F000Fu;
    t = (t | (t << 6)) & 0x03030303u;
    t = (t | (t << 3)) & 0x11111111u;
    return t;
}

// ---------------- kernel 1: binarize (coalesced) + meta zero ---------------
__global__ __launch_bounds__(256) void binarize_kernel(
    const float* __restrict__ ma, const float* __restrict__ mb,
    uint32_t* __restrict__ bitsA, uint32_t* __restrict__ bitsB,
    uint4* __restrict__ meta4)
{
    if (blockIdx.x == 0) {          // zero 8 KB of control state (ws is 0xAA)
        uint4 z; z.x = z.y = z.z = z.w = 0u;
        meta4[threadIdx.x] = z;
        meta4[threadIdx.x + 256] = z;
    }
    int g = blockIdx.x * 256 + threadIdx.x;        // float4 index
    int tensor = (g >= F4PT);                      // %64==0: wave-uniform
    int lg = tensor ? (g - F4PT) : g;
    const float* src = tensor ? mb : ma;
    vf4 v = __builtin_nontemporal_load(((const vf4*)src) + lg);
    u64 q0 = __ballot(v.x > 0.0f);
    u64 q1 = __ballot(v.y > 0.0f);
    u64 q2 = __ballot(v.z > 0.0f);
    u64 q3 = __ballot(v.w > 0.0f);
    int lane = threadIdx.x & 63;
    if (lane < 8) {
        uint32_t wd = spread4((uint32_t)(q0 >> (8 * lane)) & 0xFFu)
                    | (spread4((uint32_t)(q1 >> (8 * lane)) & 0xFFu) << 1)
                    | (spread4((uint32_t)(q2 >> (8 * lane)) & 0xFFu) << 2)
                    | (spread4((uint32_t)(q3 >> (8 * lane)) & 0xFFu) << 3);
        uint32_t* bits = tensor ? bitsB : bitsA;
        bits[((lg & ~63) >> 3) + lane] = wd;       // word = 8 float4s
    }
}

// ---------------- kernel 2: same-XCD pipeline, unique slots, plain loads ---
__global__ __launch_bounds__(PT, 1) void pipeline_kernel(
    const float* __restrict__ sa, const float* __restrict__ sb,
    uint32_t* bitsA, uint32_t* bitsB, unsigned* meta, u64* msg)
{
    unsigned* cnt    = meta;
    unsigned* winner = meta + 8;
    int* flagsA      = (int*)(meta + 16);
    int* flagsB      = (int*)(meta + 32);
    unsigned* prodF  = meta + 80;

    const int tid = threadIdx.x;
    const int wave = tid >> 6, lane = tid & 63;

    __shared__ int s_g;
    __shared__ int4 part[8];

    // ---- election (tid0), result broadcast via LDS ----
    if (tid == 0) {
        int xcc;
        asm volatile("s_getreg_b32 %0, hwreg(HW_REG_XCC_ID)" : "=s"(xcc));
        xcc &= 7;
        unsigned slot = afadd(&cnt[xcc], 1u);
        int mine = -1;
        if (slot < NG) {
            if (slot == NG - 1) {   // 8th reporter of this XCD claims the win
                unsigned exp = 0u;
                __hip_atomic_compare_exchange_strong(
                    winner, &exp, (unsigned)(xcc + 1),
                    __ATOMIC_RELAXED, __ATOMIC_RELAXED, __HIP_MEMORY_SCOPE_AGENT);
            }
            unsigned w;
            while (!(w = aload(winner))) __builtin_amdgcn_s_sleep(1);
            if (w == (unsigned)(xcc + 1)) mine = (int)slot;
        }
        s_g = mine;
    }
    __syncthreads();
    const int g = s_g;
    if (g < 0) return;              // 56 losers exit — zero interference

    const int c0 = 2 * g, c1 = 2 * g + 1;
    uint4* A4 = (uint4*)bitsA;
    uint4* B4 = (uint4*)bitsB;

    u64 b0[18], b1[18];

    // ---- load b columns (plain; dispatch boundary flushed binarize) ----
    int v0 = 0, v1 = 0;
#pragma unroll
    for (int w = 0; w < 9; ++w) {
        uint4 q0 = B4[(size_t)c0 * C4PM + tid + PT * w];
        uint4 q1 = B4[(size_t)c1 * C4PM + tid + PT * w];
        b0[2 * w] = ((u64)q0.y << 32) | q0.x; b0[2 * w + 1] = ((u64)q0.w << 32) | q0.z;
        b1[2 * w] = ((u64)q1.y << 32) | q1.x; b1[2 * w + 1] = ((u64)q1.w << 32) | q1.z;
        v0 += __popcll(b0[2 * w]) + __popcll(b0[2 * w + 1]);
        v1 += __popcll(b1[2 * w]) + __popcll(b1[2 * w + 1]);
    }
#pragma unroll
    for (int off = 32; off >= 1; off >>= 1) {
        v0 += __shfl_xor(v0, off); v1 += __shfl_xor(v1, off);
    }
    if (lane == 0) { int4 p; p.x = v0; p.y = v1; p.z = 0; p.w = 0; part[wave] = p; }
    __syncthreads();
    int pcb0 = 0, pcb1 = 0;
#pragma unroll
    for (int w = 0; w < 8; ++w) { pcb0 += part[w].x; pcb1 += part[w].y; }
    float sb0 = sb[c0], sb1 = sb[c1];
    int fb0 = 0, fb1 = 0;
    __syncthreads();   // part[] free for stage 0 writes

    for (int t = 0; t < NM; ++t) {
        int pca, fa;
        u64 a[18];

        // ---- obtain row t: all waves poll flag, then PLAIN dwordx4 loads ---
        if (g == 0) {
            pca = 0; fa = 0;
#pragma unroll
            for (int w = 0; w < 9; ++w) {
                uint4 q = A4[(size_t)t * C4PM + tid + PT * w];
                a[2 * w] = ((u64)q.y << 32) | q.x;
                a[2 * w + 1] = ((u64)q.w << 32) | q.z;
            }
        } else {
            const unsigned* fptr = &prodF[((g - 1) * 16 + t) * 4];
            unsigned v;
            do { v = aload(fptr); } while (!v);
            asm volatile("" ::: "memory");   // pin data loads below the poll
            pca = (int)((v >> 1) & 0xFFFFFu);
            fa  = (int)((v >> 21) & 1u);
            const uint4* s4 = (const uint4*)(msg + (size_t)((g - 1) * 16 + t) * U8PM);
#pragma unroll
            for (int w = 0; w < 9; ++w) {
                uint4 q = s4[tid + PT * w];
                a[2 * w]     = ((u64)q.y << 32) | q.x;
                a[2 * w + 1] = ((u64)q.w << 32) | q.z;
            }
        }

        // ---- fused popc terms (one reduction per row) ----
        int i0 = 0, i1 = 0, itr = 0, ipc = 0;
#pragma unroll
        for (int w = 0; w < 18; ++w) {
            u64 ab0 = a[w] & b0[w];
            i0 += __popcll(ab0);
            i1 += __popcll(a[w] & b1[w]);
            itr += __popcll(ab0 & b1[w]);
        }
        if (g == 0) {
#pragma unroll
            for (int w = 0; w < 18; ++w) ipc += __popcll(a[w]);
        }
#pragma unroll
        for (int off = 32; off >= 1; off >>= 1) {
            i0 += __shfl_xor(i0, off); i1 += __shfl_xor(i1, off);
            itr += __shfl_xor(itr, off); ipc += __shfl_xor(ipc, off);
        }
        if (lane == 0) {
            int4 p; p.x = i0; p.y = i1; p.z = itr; p.w = ipc; part[wave] = p;
        }
        __syncthreads();   // B2: partials visible
        int I0 = 0, I1 = 0, T = 0, PC = 0;
#pragma unroll
        for (int w = 0; w < 8; ++w) {
            int4 p = part[w];
            I0 += p.x; I1 += p.y; T += p.z; PC += p.w;
        }
        if (g == 0) pca = PC;

        float sai = sa[t];
        // ---- pair (t,c0): replicate reference fp32 arithmetic exactly ----
        bool aupd = false;
        {
            int inter = I0;
            int uni = pca + pcb0 - inter;
            float iou = (float)inter / fmaxf((float)uni, 1.0f);
            bool aw = sai > sb0;
            if (iou > 0.8f) { if (aw) fb0 = 1; else fa = 1; }
            else if (inter > 0) {
                if (aw) {
                    pcb0 -= inter;
#pragma unroll
                    for (int w = 0; w < 18; ++w) b0[w] &= ~a[w];
                } else {
                    pca -= inter; aupd = true;
#pragma unroll
                    for (int w = 0; w < 18; ++w) a[w] &= ~b0[w];
                }
            }
        }
        // ---- pair (t,c1): exact inter via speculative triple term ----
        {
            int inter = aupd ? (I1 - T) : I1;
            int uni = pca + pcb1 - inter;
            float iou = (float)inter / fmaxf((float)uni, 1.0f);
            bool aw = sai > sb1;
            if (iou > 0.8f) { if (aw) fb1 = 1; else fa = 1; }
            else if (inter > 0) {
                if (aw) {
                    pcb1 -= inter;
#pragma unroll
                    for (int w = 0; w < 18; ++w) b1[w] &= ~a[w];
                } else {
                    pca -= inter;
#pragma unroll
                    for (int w = 0; w < 18; ++w) a[w] &= ~b1[w];
                }
            }
        }

        // ---- forward / finalize row ----
        if (g < NG - 1) {
            uint4* so = (uint4*)(msg + (size_t)(g * 16 + t) * U8PM);
#pragma unroll
            for (int w = 0; w < 9; ++w) {
                uint4 q;
                q.x = (uint32_t)a[2 * w];     q.y = (uint32_t)(a[2 * w] >> 32);
                q.z = (uint32_t)a[2 * w + 1]; q.w = (uint32_t)(a[2 * w + 1] >> 32);
                so[tid + PT * w] = q;          // plain: write-through into L2
            }
            __syncthreads();   // B3: every wave's vmcnt(0) -> data in L2
            if (tid == 0)      // flag strictly after data
                astore(&prodF[(g * 16 + t) * 4],
                       1u | ((unsigned)pca << 1) | ((unsigned)fa << 21));
        } else {
            uint4* Ar = A4 + (size_t)t * C4PM;
#pragma unroll
            for (int w = 0; w < 9; ++w) {
                uint4 q;
                q.x = (uint32_t)a[2 * w];     q.y = (uint32_t)(a[2 * w] >> 32);
                q.z = (uint32_t)a[2 * w + 1]; q.w = (uint32_t)(a[2 * w + 1] >> 32);
                Ar[tid + PT * w] = q;
            }
            if (tid == 0) flagsA[t] = fa;
            __syncthreads();   // B3: part[] anti-race across stages
        }
    }

    // final b columns + flags; dispatch-end flush publishes to expand
    uint4* Wc0 = B4 + (size_t)c0 * C4PM;
    uint4* Wc1 = B4 + (size_t)c1 * C4PM;
#pragma unroll
    for (int w = 0; w < 9; ++w) {
        uint4 q0, q1;
        q0.x = (uint32_t)b0[2 * w];     q0.y = (uint32_t)(b0[2 * w] >> 32);
        q0.z = (uint32_t)b0[2 * w + 1]; q0.w = (uint32_t)(b0[2 * w + 1] >> 32);
        q1.x = (uint32_t)b1[2 * w];     q1.y = (uint32_t)(b1[2 * w] >> 32);
        q1.z = (uint32_t)b1[2 * w + 1]; q1.w = (uint32_t)(b1[2 * w + 1] >> 32);
        Wc0[tid + PT * w] = q0;
        Wc1[tid + PT * w] = q1;
    }
    if (tid == 0) { flagsB[c0] = fb0; flagsB[c1] = fb1; }
}

// ---------------- kernel 3: expand (coalesced, NT stores) ------------------
__global__ __launch_bounds__(256) void expand_kernel(
    const uint32_t* __restrict__ bitsA, const uint32_t* __restrict__ bitsB,
    const int* __restrict__ meta, float* __restrict__ out)
{
    int g = blockIdx.x * 256 + threadIdx.x;        // float4 index
    int tensor = (g >= F4PT);
    int lg = tensor ? (g - F4PT) : g;
    const uint32_t* bits = tensor ? bitsB : bitsA;
    const int* flags = meta + (tensor ? 32 : 16);
    int m = lg / F4PM;
    bool keep = (flags[m] == 0);
    uint32_t wd = keep ? bits[lg >> 3] : 0u;
    int sh = (lg & 7) * 4;
    vf4 o;
    o.x = ((wd >> (sh + 0)) & 1u) ? 1.0f : 0.0f;
    o.y = ((wd >> (sh + 1)) & 1u) ? 1.0f : 0.0f;
    o.z = ((wd >> (sh + 2)) & 1u) ? 1.0f : 0.0f;
    o.w = ((wd >> (sh + 3)) & 1u) ? 1.0f : 0.0f;
    __builtin_nontemporal_store(o, ((vf4*)out) + g);
    if (g < 2 * NM) {   // keep_a / keep_b tail (flagsA,flagsB contiguous)
        out[(size_t)2 * NM * HW_P + g] = meta[16 + g] ? 0.0f : 1.0f;
    }
}

extern "C" void kernel_launch(void* const* d_in, const int* in_sizes, int n_in,
                              void* d_out, int out_size, void* d_ws, size_t ws_size,
                              hipStream_t stream)
{
    const float* ma = (const float*)d_in[0];
    const float* mb = (const float*)d_in[1];
    const float* sa = (const float*)d_in[2];
    const float* sb = (const float*)d_in[3];
    float* out = (float*)d_out;
    char* ws = (char*)d_ws;

    uint32_t* bitsA = (uint32_t*)(ws);             // 1,179,648 B
    uint32_t* bitsB = (uint32_t*)(ws + 1179648);   // 1,179,648 B
    unsigned* meta  = (unsigned*)(ws + 2359296);   // 8192 B, zeroed by binarize
    u64* msg        = (u64*)(ws + 2367488);        // 7*16 unique slots * 73,728 B

    binarize_kernel<<<18432, 256, 0, stream>>>(ma, mb, bitsA, bitsB,
                                               (uint4*)meta);
    pipeline_kernel<<<EWG, PT, 0, stream>>>(sa, sb, bitsA, bitsB, meta, msg);
    expand_kernel<<<18432, 256, 0, stream>>>(bitsA, bitsB, (const int*)meta, out);
}